// Round 1
// baseline (238.063 us; speedup 1.0000x reference)
//
#include <hip/hip_runtime.h>
#include <math.h>

namespace {
constexpr int T    = 4096;
constexpr int C    = 64;
constexpr int NCH  = 4;
constexpr int TDAF = 50;
constexpr int TT   = 128;          // t-steps per tile
constexpr int NT   = T / TT;       // 32 tiles
constexpr int XPAD = 76;           // padded floats per x-row in LDS (304B, 16B-aligned)
constexpr int THREADS = 512;       // 8 waves
constexpr double LEAK = 0.9;
}

__global__ __launch_bounds__(THREADS, 2)
void lif_fused(const float* __restrict__ x,     // [B,T,C]
               const float* __restrict__ tda,   // [B,TDAF]
               const float* __restrict__ Wsp,   // [NCH,C]
               const float* __restrict__ lat,   // [NCH,NCH]
               const float* __restrict__ Wtda,  // [NCH,TDAF]
               const float* __restrict__ btda,  // [NCH]
               float* __restrict__ out)         // [B,T,NCH]
{
  __shared__ float  xl[2][TT * XPAD];   // ~77.8 KB
  __shared__ double wl[NCH * C];        // W_eff, [n][c]
  __shared__ double projl[TT * NCH];
  __shared__ float  spikel[TT * NCH];
  __shared__ double thl[NCH];

  const int b   = blockIdx.x;
  const int tid = threadIdx.x;
  const int n   = tid & 3;
  const int tl  = tid >> 2;

  // ---- prologue: dynamic threshold + W_eff = W_spatial^T @ lateral (f64) ----
  if (tid < NCH) {
    double z = (double)btda[tid];
    for (int j = 0; j < TDAF; ++j)
      z += (double)tda[b * TDAF + j] * (double)Wtda[tid * TDAF + j];
    thl[tid] = 1.0 + 0.3 / (1.0 + exp(-z));
  }
  if (tid < NCH * C) {
    const int c = tid >> 2, nn = tid & 3;
    double s = 0.0;
    for (int m = 0; m < NCH; ++m)
      s += (double)Wsp[m * C + c] * (double)lat[m * NCH + nn];
    wl[nn * C + c] = s;
  }
  __syncthreads();

  // per-thread W_eff column (f64, static-indexed -> stays in VGPRs)
  double w[C];
  #pragma unroll
  for (int j = 0; j < C; ++j) w[j] = wl[n * C + j];
  const double th = thl[n];

  const float4* gx = reinterpret_cast<const float4*>(x) + (size_t)b * (T * C / 4);
  // per tile: TT*C/4 = 2048 float4; 4 per thread.

  float4 ra[4], rb[4];
  #pragma unroll
  for (int r = 0; r < 4; ++r) ra[r] = gx[tid + THREADS * r];  // tile 0

  // scan state (meaningful in lanes tid<4 only):
  // pre = pre-reset membrane of previous step, sflag = spike of previous step
  double pre = 0.0;
  bool sflag = true;   // mem0 = 0  =>  pre_0 = p_0 (select path)

  auto stage = [&](int buf, const float4* rr) {
    #pragma unroll
    for (int r = 0; r < 4; ++r) {
      const int f  = tid + THREADS * r;   // float4 index within tile
      const int t  = f >> 4;              // 16 float4 per 64-float row
      const int c4 = (f & 15) << 2;
      *reinterpret_cast<float4*>(&xl[buf][t * XPAD + c4]) = rr[r];
    }
  };
  auto prefetch = [&](int k, float4* rr) {
    const float4* src = gx + (size_t)k * (TT * C / 4);
    #pragma unroll
    for (int r = 0; r < 4; ++r) rr[r] = src[tid + THREADS * r];
  };
  auto tilework = [&](int buf, int k) {
    __syncthreads();                       // x tile staged; spikel of k-1 copied out
    // ---- proj: thread (tl, n) does one 64-term f64 dot ----
    const float* row = &xl[buf][tl * XPAD];
    double a0 = 0.0, a1 = 0.0;
    #pragma unroll
    for (int q = 0; q < 16; ++q) {
      const float4 v = *reinterpret_cast<const float4*>(&row[4 * q]);
      a0 = fma((double)v.x, w[4 * q + 0], a0);
      a1 = fma((double)v.y, w[4 * q + 1], a1);
      a0 = fma((double)v.z, w[4 * q + 2], a0);
      a1 = fma((double)v.w, w[4 * q + 3], a1);
    }
    projl[tid] = a0 + a1;                  // tid == tl*4+n
    __syncthreads();
    // ---- serial LIF scan: 4 lanes, one per channel ----
    if (tid < NCH) {
      #pragma unroll 4
      for (int t = 0; t < TT; ++t) {
        const double p  = projl[t * NCH + tid];
        const double ac = fma(LEAK, pre, p);   // leak path
        pre   = sflag ? p : ac;                // reset applied to PREVIOUS step
        sflag = (pre >= th);
        spikel[t * NCH + tid] = sflag ? 1.0f : 0.0f;
      }
    }
    __syncthreads();
    // ---- coalesced spike copy-out (512 values, 512 threads) ----
    out[((size_t)b * T + (size_t)k * TT) * NCH + tid] = spikel[tid];
  };

  for (int k = 0; k < NT; k += 2) {
    stage(0, ra);
    if (k + 1 < NT) prefetch(k + 1, rb);   // in flight across compute+scan
    tilework(0, k);
    stage(1, rb);
    if (k + 2 < NT) prefetch(k + 2, ra);
    tilework(1, k + 1);
  }
}

extern "C" void kernel_launch(void* const* d_in, const int* in_sizes, int n_in,
                              void* d_out, int out_size, void* d_ws, size_t ws_size,
                              hipStream_t stream) {
  const float* x    = (const float*)d_in[0];
  const float* tda  = (const float*)d_in[1];
  const float* Wsp  = (const float*)d_in[2];
  const float* lat  = (const float*)d_in[3];
  const float* Wtda = (const float*)d_in[4];
  const float* btda = (const float*)d_in[5];
  float* out = (float*)d_out;
  const int B = in_sizes[0] / (T * C);
  lif_fused<<<B, THREADS, 0, stream>>>(x, tda, Wsp, lat, Wtda, btda, out);
}